// Round 9
// baseline (2416.304 us; speedup 1.0000x reference)
//
#include <hip/hip_runtime.h>
#include <hip/hip_fp16.h>
#include <math.h>

#define Bsz 128
#define Tsz 512
#define Hsz 1024
#define NM  8
#define MS  128
#define NT  512

// ---------------- workspace layout (bytes) ----------------
// WB0  @0       : float[16384]      pair (0,0), [row*128 + j]
// WBh  @65536   : half[35*16384]    pairs 1..35 (tri order), [j*128 + row]
// SpXg @1212416 : float[128][2][2048]  per-element snapshot double buffer
// Ohig @3309568 : float[128][2][2]
// rdy  @3311616 : int[128]
// fpg  @3312128 : int[128]
#define WB0_OFF  0
#define WBH_OFF  65536
#define SPX_OFF  1212416
#define OHI_OFF  3309568
#define RDY_OFF  3311616
#define FPG_OFF  3312128

// ---------------------------------------------------------------------------
__global__ __launch_bounds__(256)
void retile_whh(const float* __restrict__ W, float* __restrict__ WB0,
                __half* __restrict__ WBh, int* __restrict__ readyg,
                int* __restrict__ fprogg) {
    __shared__ float tile[MS][MS + 1];
    const int p = blockIdx.x;
    const int t = threadIdx.x;
    if (p == 0) {
        for (int idx = t; idx < MS * MS; idx += 256) {
            const int row = idx >> 7, j = idx & (MS - 1);
            WB0[idx] = W[row * Hsz + j];
        }
        for (int i = t; i < Bsz; i += 256) { readyg[i] = 0; fprogg[i] = 0; }
        return;
    }
    int c = 0;
    while ((c + 1) * (c + 2) / 2 <= p) ++c;
    const int r = p - c * (c + 1) / 2;
    for (int idx = t; idx < MS * MS; idx += 256) {
        const int row = idx >> 7, j = idx & (MS - 1);
        tile[row][j] = W[(size_t)(r * MS + row) * Hsz + c * MS + j];
    }
    __syncthreads();
    __half* wb = WBh + (size_t)(p - 1) * MS * MS;
    for (int idx = t; idx < MS * MS; idx += 256) {
        const int j = idx >> 7, row = idx & (MS - 1);
        wb[idx] = __float2half(tile[row][j]);
    }
}

__device__ __forceinline__ float fast_tanh(float x) {
    const float e = __expf(2.0f * x);
    return 1.0f - 2.0f * __builtin_amdgcn_rcpf(e + 1.0f);
}

union H4 { short4 s4; __half2 h2[2]; };

// R7's coalesced fp16 pair reduction: 128 threads per pair, thread owns rows
// row4..row4+3 over j-range jq*32..+31; parts merged by shfl_xor(32).
__device__ __forceinline__ float4 pair_body(const __half* __restrict__ wsrc,
                                            const float* __restrict__ hc,
                                            int jq, int row4) {
    const __half* wp = wsrc + (size_t)(jq * 32) * MS + row4;
    float4 acc = {0.f, 0.f, 0.f, 0.f};
    #pragma unroll 8
    for (int jj = 0; jj < 32; ++jj) {
        const float hj = hc[jq * 32 + jj];
        H4 u; u.s4 = *(const short4*)(wp + (size_t)jj * MS);
        const float2 f01 = __half22float2(u.h2[0]);
        const float2 f23 = __half22float2(u.h2[1]);
        acc.x += f01.x * hj; acc.y += f01.y * hj;
        acc.z += f23.x * hj; acc.w += f23.y * hj;
    }
    return acc;
}
__device__ __forceinline__ void pair_commit(float* __restrict__ spdst, // [2][128]
                                            float4 acc, int part, bool wr_gate,
                                            int row4) {
    acc.x += __shfl_xor(acc.x, 32, 64); acc.y += __shfl_xor(acc.y, 32, 64);
    acc.z += __shfl_xor(acc.z, 32, 64); acc.w += __shfl_xor(acc.w, 32, 64);
    if (wr_gate) *(float4*)(spdst + part * MS + row4) = acc;
}

// ---------------------------------------------------------------------------
// Paired-block Clockwork RNN. grid = 256:
//   blocks 0..127   = S role (modules 4..7 of element b=blockIdx)
//   blocks 128..255 = F role (modules 0..3 of element b=blockIdx-128)
// S is self-contained (module m>=4 reads cols >= m only); it runs its 32
// epochs (t=16e) autonomously, publishing per-epoch: merged cross partials
// S[r<4][c>=4] (16x128 f32) + hi fc contribution, double-buffered in global,
// throttled by F's progress counter. Agent-scope release/acquire for the
// cross-XCD handoff. F runs the 512 dense steps on modules 0..3 only.
// ---------------------------------------------------------------------------
__global__ __launch_bounds__(NT)
void cwrnn_kernel(const float* __restrict__ x,
                  const float* __restrict__ W_ih,
                  const float* __restrict__ fc_w,
                  const float* __restrict__ fc_b,
                  const float* __restrict__ enc_w,
                  const float* __restrict__ WB0,
                  const __half* __restrict__ WBh,
                  float* __restrict__ SpXg,   // [128][2][2048]
                  float* __restrict__ Ohig,   // [128][2][2]
                  int* __restrict__ readyg,   // [128]
                  int* __restrict__ fprogg,   // [128]
                  float* __restrict__ out)    // [B, T, 2]
{
    __shared__ __align__(16) char smem[103040];
    const int tid  = threadIdx.x;
    const int lane = tid & 63;
    const int wave = tid >> 6;

    // shared refresh mapping (R7's, conflict-free)
    const int slot4 = tid >> 7;
    const int s     = tid & 127;
    const int row4  = (s & 31) * 4;
    const int jq    = s >> 5;
    const int part  = (tid >> 6) & 1;
    const bool wr_gate = ((tid >> 5) & 1) == 0;

    if (blockIdx.x < Bsz) {
        // ================= role S: modules 4..7 =================
        const int b = blockIdx.x;
        float*  SpS  = (float*) (smem);            // [10][2][128] own pairs
        float*  SpXp = (float*) (smem + 10240);    // [16][2][128] cross pairs
        float*  h_hi = (float*) (smem + 26624);    // [512]
        float2* x_s  = (float2*)(smem + 28672);    // [513]
        float2* wih  = (float2*)(smem + 32784);    // [512] rows 512..1023
        float*  fcw  = (float*) (smem + 36880);    // [1024] interleaved
        float2* wred = (float2*)(smem + 40976);    // [8]

        const float2* xb = (const float2*)(x + (size_t)b * (Tsz + 1) * 2);
        for (int i = tid; i < Tsz + 1; i += NT) x_s[i] = xb[i];
        for (int i = tid; i < 512; i += NT) wih[i] = ((const float2*)W_ih)[512 + i];
        for (int i = tid; i < 512; i += NT) {
            fcw[2 * i]     = fc_w[512 + i];
            fcw[2 * i + 1] = fc_w[Hsz + 512 + i];
        }
        {
            const float2 x0 = xb[0];
            for (int i = tid; i < 512; i += NT) {
                const float2 ew = ((const float2*)enc_w)[512 + i];
                h_hi[i] = x0.x * ew.x + x0.y * ew.y;
            }
        }
        __syncthreads();

        auto sp_dst = [&](int r, int c) -> float* {
            if (r < 4) return SpXp + ((c - 4) * 4 + r) * 2 * MS;
            return SpS + ((c - 4) * (c - 3) / 2 + (r - 4)) * 2 * MS;
        };
        auto refreshS = [&](int chi) {     // pairs (r<=c, c) for c=4..chi
            int n = 0;
            for (int c = 4; c <= chi; ++c)
                for (int r = 0; r <= c; ++r)
                    if (((n++) & 3) == slot4) {
                        const int p = c * (c + 1) / 2 + r;
                        float4 acc = pair_body(WBh + (size_t)(p - 1) * MS * MS,
                                               h_hi + (c - 4) * MS, jq, row4);
                        pair_commit(sp_dst(r, c), acc, part, wr_gate, row4);
                    }
        };
        auto publish = [&](int slot) {     // merge parts -> global snapshot
            float* dst = SpXg + ((size_t)b * 2 + slot) * 2048;
            for (int i = tid; i < 2048; i += NT) {
                const float* sp = SpXp + (i >> 7) * 2 * MS;
                dst[i] = sp[i & 127] + sp[MS + (i & 127)];
            }
        };

        refreshS(7);                       // init from h0 (snap -1)
        __syncthreads();
        publish(0);
        __syncthreads();
        if (tid == 0) {
            __threadfence();
            __hip_atomic_store(&readyg[b], 1, __ATOMIC_RELEASE, __HIP_MEMORY_SCOPE_AGENT);
        }

        for (int e = 0; e < 32; ++e) {
            const int t = e << 4;
            const int KH = (e == 0) ? 3 : min(__ffs(e) - 1, 3);
            const float2 xt = x_s[t + 1];
            const int nrowsH = (KH + 1) * MS;
            if (tid < nrowsH) {            // P1 for active hi modules
                const int m = 4 + (tid >> 7);
                const int il = tid & 127;
                const float2 wv = wih[tid];
                float pre = xt.x * wv.x + xt.y * wv.y;
                for (int c = m; c < 8; ++c) {
                    const float* sp = SpS + ((c - 4) * (c - 3) / 2 + (m - 4)) * 2 * MS;
                    pre += sp[il] + sp[MS + il];
                }
                h_hi[tid] = fast_tanh(pre);
            }
            __syncthreads();
            {                              // hi fc contribution (full 512 rows)
                const float h = h_hi[tid];
                float p0 = h * fcw[2 * tid], p1 = h * fcw[2 * tid + 1];
                #pragma unroll
                for (int o = 32; o > 0; o >>= 1) {
                    p0 += __shfl_down(p0, o, 64);
                    p1 += __shfl_down(p1, o, 64);
                }
                if (lane == 0) wred[wave] = make_float2(p0, p1);
            }
            refreshS(4 + KH);              // refresh pairs of updated columns
            __syncthreads();
            if (tid == 0 && e >= 2) {      // throttle: slot reused from snap e-2
                const int need = 16 * (e - 2) + 1;
                while (__hip_atomic_load(&fprogg[b], __ATOMIC_ACQUIRE,
                                         __HIP_MEMORY_SCOPE_AGENT) < need)
                    __builtin_amdgcn_s_sleep(16);
            }
            __syncthreads();
            const int slot = (e + 1) & 1;
            publish(slot);
            if (tid == 0) {
                float o0 = 0.f, o1 = 0.f;
                #pragma unroll
                for (int w = 0; w < 8; ++w) { o0 += wred[w].x; o1 += wred[w].y; }
                Ohig[(b * 2 + slot) * 2]     = o0;
                Ohig[(b * 2 + slot) * 2 + 1] = o1;
            }
            __syncthreads();
            if (tid == 0) {
                __threadfence();
                __hip_atomic_store(&readyg[b], e + 2, __ATOMIC_RELEASE,
                                   __HIP_MEMORY_SCOPE_AGENT);
            }
        }
    } else {
        // ================= role F: modules 0..3 =================
        const int b = blockIdx.x - Bsz;
        __half* wlds  = (__half*)(smem);             // pairs 1,2 fp16 (64 KB)
        float*  SpF   = (float*) (smem + 65536);     // [10][2][128] (p=1..9)
        float*  SpXl  = (float*) (smem + 75776);     // [16][128] snapshot copy
        float*  Sp00  = (float*) (smem + 83968);     // [128]
        float*  h_lo  = (float*) (smem + 84480);     // [512]
        float2* x_s   = (float2*)(smem + 86528);     // [513]
        float2* wih   = (float2*)(smem + 90640);     // [512] rows 0..511
        float*  fcw   = (float*) (smem + 94736);     // [1024] interleaved
        float*  out_s = (float*) (smem + 98832);     // [1024]
        float2* ored  = (float2*)(smem + 102928);    // [4]
        float*  ohi   = (float*) (smem + 102960);    // [2]

        const float2* xb = (const float2*)(x + (size_t)b * (Tsz + 1) * 2);
        for (int i = tid; i < Tsz + 1; i += NT) x_s[i] = xb[i];
        for (int i = tid; i < 512; i += NT) wih[i] = ((const float2*)W_ih)[i];
        for (int i = tid; i < 512; i += NT) {
            fcw[2 * i]     = fc_w[i];
            fcw[2 * i + 1] = fc_w[Hsz + i];
        }
        for (int i = tid; i < 2 * MS * MS / 4; i += NT)
            ((short4*)wlds)[i] = ((const short4*)WBh)[i];   // pairs 1,2
        const float fb0 = fc_b[0], fb1 = fc_b[1];

        const int row00 = tid >> 2, jc = tid & 3;
        float4 w00[8];
        #pragma unroll
        for (int u = 0; u < 8; ++u) {
            const int uu = (u + 2 * jc) & 7;
            w00[u] = *(const float4*)(WB0 + row00 * MS + jc * 32 + uu * 4);
        }
        {
            const float2 x0 = xb[0];
            for (int i = tid; i < 512; i += NT) {
                const float2 ew = ((const float2*)enc_w)[i];
                h_lo[i] = x0.x * ew.x + x0.y * ew.y;
            }
        }
        __syncthreads();

        auto refresh00 = [&]() {
            float a = 0.f;
            #pragma unroll
            for (int u = 0; u < 8; ++u) {
                const int uu = (u + 2 * jc) & 7;
                const float4 hv = *(const float4*)(h_lo + jc * 32 + uu * 4);
                a += w00[u].x * hv.x + w00[u].y * hv.y + w00[u].z * hv.z + w00[u].w * hv.w;
            }
            a += __shfl_xor(a, 1, 64);
            a += __shfl_xor(a, 2, 64);
            if (jc == 0) Sp00[row00] = a;
        };
        auto refreshF = [&](int cmax) {    // pairs (r<=c, c) for c=1..cmax
            int n = 0;
            for (int c = 1; c <= cmax; ++c)
                for (int r = 0; r <= c; ++r)
                    if (((n++) & 3) == slot4) {
                        const int p = c * (c + 1) / 2 + r;
                        const __half* w = (p <= 2)
                            ? (wlds + (size_t)(p - 1) * MS * MS)
                            : (WBh  + (size_t)(p - 1) * MS * MS);
                        float4 acc = pair_body(w, h_lo + c * MS, jq, row4);
                        pair_commit(SpF + p * 2 * MS, acc, part, wr_gate, row4);
                    }
        };

        refresh00();
        refreshF(3);
        if (tid == 0) {                    // wait snap -1
            while (__hip_atomic_load(&readyg[b], __ATOMIC_ACQUIRE,
                                     __HIP_MEMORY_SCOPE_AGENT) < 1)
                __builtin_amdgcn_s_sleep(2);
        }
        __syncthreads();
        {
            const float* src = SpXg + (size_t)b * 2 * 2048;   // slot 0
            for (int i = tid; i < 2048; i += NT)
                SpXl[i] = __hip_atomic_load(&src[i], __ATOMIC_RELAXED,
                                            __HIP_MEMORY_SCOPE_AGENT);
        }
        __syncthreads();

        for (int t = 0; t < Tsz; ++t) {
            const int A  = (t == 0) ? 7 : min(__ffs(t) - 1, 7);
            const int A3 = min(A, 3);
            const int nrows = (A3 + 1) * MS;
            const float2 xt = x_s[t + 1];
            const bool bnd = (t & 15) == 0;
            if (bnd && tid == 0) {         // need snap t/16 (for O_hi at out[t])
                const int need = (t >> 4) + 2;
                while (__hip_atomic_load(&readyg[b], __ATOMIC_ACQUIRE,
                                         __HIP_MEMORY_SCOPE_AGENT) < need)
                    __builtin_amdgcn_s_sleep(2);
            }
            // ---- P1 ----
            if (tid < nrows) {
                const int r = tid >> 7, il = tid & 127;
                const float2 wv = wih[tid];
                float pre = xt.x * wv.x + xt.y * wv.y;
                if (r == 0) pre += Sp00[il];
                #pragma unroll
                for (int c = 1; c < 4; ++c)
                    if (c >= r) {
                        const float* sp = SpF + (c * (c + 1) / 2 + r) * 2 * MS;
                        pre += sp[il] + sp[MS + il];
                    }
                #pragma unroll
                for (int cc = 0; cc < 4; ++cc)
                    pre += SpXl[(cc * 4 + r) * MS + il];
                h_lo[tid] = fast_tanh(pre);
            }
            __syncthreads();               // B1
            // ---- refresh window ----
            if (bnd) {                     // pull snapshot t/16 into LDS
                const int slot = ((t >> 4) + 1) & 1;
                const float* src = SpXg + ((size_t)b * 2 + slot) * 2048;
                for (int i = tid; i < 2048; i += NT)
                    SpXl[i] = __hip_atomic_load(&src[i], __ATOMIC_RELAXED,
                                                __HIP_MEMORY_SCOPE_AGENT);
                if (tid == 0) {
                    ohi[0] = __hip_atomic_load(&Ohig[(b * 2 + slot) * 2],
                                               __ATOMIC_RELAXED, __HIP_MEMORY_SCOPE_AGENT);
                    ohi[1] = __hip_atomic_load(&Ohig[(b * 2 + slot) * 2 + 1],
                                               __ATOMIC_RELAXED, __HIP_MEMORY_SCOPE_AGENT);
                }
            }
            refreshF(A3);                  // VMEM streams issued early
            refresh00();
            // ---- P2: wave w owns module w (stale ored = still correct) ----
            if (wave <= A3) {
                const int j2 = wave * MS + lane * 2;
                const float2 h2 = *(const float2*)&h_lo[j2];
                const float4 fw = *(const float4*)&fcw[2 * j2];
                float a0 = h2.x * fw.x + h2.y * fw.z;
                float a1 = h2.x * fw.y + h2.y * fw.w;
                #pragma unroll
                for (int o = 32; o > 0; o >>= 1) {
                    a0 += __shfl_down(a0, o, 64);
                    a1 += __shfl_down(a1, o, 64);
                }
                if (lane == 0) ored[wave] = make_float2(a0, a1);
            }
            __syncthreads();               // B2
            if (tid == 0) {
                float o0 = fb0 + ohi[0], o1 = fb1 + ohi[1];
                #pragma unroll
                for (int m = 0; m < 4; ++m) { o0 += ored[m].x; o1 += ored[m].y; }
                out_s[2 * t]     = o0;
                out_s[2 * t + 1] = o1;
                __hip_atomic_store(&fprogg[b], t + 1, __ATOMIC_RELEASE,
                                   __HIP_MEMORY_SCOPE_AGENT);
            }
        }
        __syncthreads();
        float* outb = out + (size_t)b * Tsz * 2;
        for (int i = tid; i < Tsz * 2; i += NT) outb[i] = out_s[i];
    }
}

// ---------------------------------------------------------------------------
extern "C" void kernel_launch(void* const* d_in, const int* in_sizes, int n_in,
                              void* d_out, int out_size, void* d_ws, size_t ws_size,
                              hipStream_t stream) {
    const float* x     = (const float*)d_in[0];
    const float* W_ih  = (const float*)d_in[1];
    const float* W_hh  = (const float*)d_in[2];
    const float* fc_w  = (const float*)d_in[3];
    const float* fc_b  = (const float*)d_in[4];
    const float* enc_w = (const float*)d_in[5];
    float* outp = (float*)d_out;
    char* ws = (char*)d_ws;
    float*  WB0    = (float*) (ws + WB0_OFF);
    __half* WBh    = (__half*)(ws + WBH_OFF);
    float*  SpXg   = (float*) (ws + SPX_OFF);
    float*  Ohig   = (float*) (ws + OHI_OFF);
    int*    readyg = (int*)   (ws + RDY_OFF);
    int*    fprogg = (int*)   (ws + FPG_OFF);

    retile_whh<<<36, 256, 0, stream>>>(W_hh, WB0, WBh, readyg, fprogg);
    cwrnn_kernel<<<2 * Bsz, NT, 0, stream>>>(x, W_ih, fc_w, fc_b, enc_w,
                                             WB0, WBh, SpXg, Ohig,
                                             readyg, fprogg, outp);
}

// Round 10
// 1685.051 us; speedup vs baseline: 1.4340x; 1.4340x over previous
//
#include <hip/hip_runtime.h>
#include <hip/hip_fp16.h>

#define Bsz 128
#define Tsz 512
#define Hsz 1024
#define MS  128
#define NT  576   // 9 waves: 0..7 = modules, 8 = output assembly

typedef __attribute__((ext_vector_type(2))) _Float16 h2_t;
union U32H2 { unsigned u; h2_t h; __half2 hh; };

__device__ __forceinline__ float fdot2u(unsigned w, unsigned h, float acc) {
#if __has_builtin(__builtin_amdgcn_fdot2)
    U32H2 a, b; a.u = w; b.u = h;
    return __builtin_amdgcn_fdot2(a.h, b.h, acc, false);
#else
    U32H2 a, b; a.u = w; b.u = h;
    float2 fa = __half22float2(a.hh), fb = __half22float2(b.hh);
    return acc + fa.x * fb.x + fa.y * fb.y;
#endif
}
__device__ __forceinline__ unsigned packh2(float a, float b) {
    U32H2 u; u.hh = __floats2half2_rn(a, b); return u.u;
}
__device__ __forceinline__ float fast_tanh(float x) {
    const float e = __expf(2.0f * x);
    return 1.0f - 2.0f * __builtin_amdgcn_rcpf(e + 1.0f);
}
__device__ __forceinline__ int ld_acq(int* p) {
    return __hip_atomic_load(p, __ATOMIC_ACQUIRE, __HIP_MEMORY_SCOPE_WORKGROUP);
}
__device__ __forceinline__ void st_rel(int* p, int v) {
    __hip_atomic_store(p, v, __ATOMIC_RELEASE, __HIP_MEMORY_SCOPE_WORKGROUP);
}

// ---------------------------------------------------------------------------
// Retile W_hh block (r,c), tri p=c(c+1)/2+r, into fp16 j-pair dwords:
//   WPg[p*8192 + row*64 + jd] = pack(W[r*128+row][c*128+2jd], ...[2jd+1])
// ---------------------------------------------------------------------------
__global__ __launch_bounds__(256)
void retile(const float* __restrict__ W, unsigned* __restrict__ WPg) {
    const int p = blockIdx.x;
    int c = 0; while ((c + 1) * (c + 2) / 2 <= p) ++c;
    const int r = p - c * (c + 1) / 2;
    const float* src = W + (size_t)(r * MS) * Hsz + c * MS;
    unsigned* dst = WPg + (size_t)p * 8192;
    for (int i = threadIdx.x; i < 8192; i += 256) {
        const int row = i >> 6, jd = i & 63;
        dst[i] = packh2(src[row * Hsz + 2 * jd], src[row * Hsz + 2 * jd + 1]);
    }
}

// ---------------------------------------------------------------------------
// Wave-async Clockwork RNN. grid=128 (1 block/element), 9 waves, NO
// __syncthreads in the step loop. Wave m: module m's P1 + O[m] + all S[r][m].
// Wave 8: per-step output assembly. LDS counters (acquire/release, WG scope):
//   pub_s[m] = published epoch+2 (INIT=1), cons_s[m] = steps consumed,
//   sd0_s = wave0 h-steps done, outd_s = outputs done.
// Slots: epoch k -> parity k&1; INIT -> slot 1. Producer overwrites slot k&1
// only after consumers pass step (k-1)*2^m (2-epoch window => no deadlock:
// every wave releases cons BEFORE any throttle spin).
// ---------------------------------------------------------------------------
__global__ __launch_bounds__(NT, 3)
void cwrnn_kernel(const float* __restrict__ x,
                  const float* __restrict__ W_ih,
                  const float* __restrict__ fc_w,
                  const float* __restrict__ fc_b,
                  const float* __restrict__ enc_w,
                  const unsigned* __restrict__ WPg,
                  float* __restrict__ out)
{
    __shared__ float Sp[35][2][MS];                 // pairs tri(r,c)-1, c>=1
    __shared__ __align__(16) unsigned hbuf[8][2][64]; // packed fp16 h dwords
    __shared__ float2 x_s[Tsz + 1];
    __shared__ float O_s[8][2][2];
    __shared__ int pub_s[8], cons_s[8], sd0_s, outd_s;

    const int tid  = threadIdx.x;
    const int lane = tid & 63;
    const int wv   = tid >> 6;
    const int b    = blockIdx.x;
    const float2* xb = (const float2*)(x + (size_t)b * (Tsz + 1) * 2);

    for (int i = tid; i < Tsz + 1; i += NT) x_s[i] = xb[i];
    if (tid < 8) { pub_s[tid] = 0; cons_s[tid] = 0; }
    if (tid == 0) { sd0_s = 0; outd_s = 0; }
    __syncthreads();                                 // ONLY barrier

    if (wv == 0) {
        // ================= wave 0: module 0 (serial critical path) =========
        const int R0 = 2 * lane, R1 = R0 + 1;
        const float2 wihA = ((const float2*)W_ih)[R0];
        const float2 wihB = ((const float2*)W_ih)[R1];
        const float2 eA = ((const float2*)enc_w)[R0];
        const float2 eB = ((const float2*)enc_w)[R1];
        unsigned w00[128];                           // rows R0,R1 of W00, fp16
        {
            const unsigned* wp = WPg;                // pair 0
            #pragma unroll
            for (int s = 0; s < 64; ++s) {
                w00[s]      = wp[R0 * 64 + s];
                w00[64 + s] = wp[R1 * 64 + s];
            }
        }
        float a0s, a1s;                              // S[0][0] rows R0,R1
        auto mv00 = [&](int slot) {
            const unsigned* hb = &hbuf[0][slot][0];
            float n0 = 0.f, n1 = 0.f;
            #pragma unroll
            for (int q = 0; q < 16; ++q) {
                const uint4 h4 = *(const uint4*)(hb + 4 * q);
                n0 = fdot2u(w00[4*q+0], h4.x, n0); n1 = fdot2u(w00[64+4*q+0], h4.x, n1);
                n0 = fdot2u(w00[4*q+1], h4.y, n0); n1 = fdot2u(w00[64+4*q+1], h4.y, n1);
                n0 = fdot2u(w00[4*q+2], h4.z, n0); n1 = fdot2u(w00[64+4*q+2], h4.z, n1);
                n0 = fdot2u(w00[4*q+3], h4.w, n0); n1 = fdot2u(w00[64+4*q+3], h4.w, n1);
            }
            a0s = n0; a1s = n1;
        };
        {   // INIT
            const float2 x0 = x_s[0];
            hbuf[0][1][lane] = packh2(x0.x * eA.x + x0.y * eA.y,
                                      x0.x * eB.x + x0.y * eB.y);
            mv00(1);
        }
        for (int t = 0; t < Tsz; ++t) {
            const int d = t - 1;
            #pragma unroll
            for (int c = 1; c < 8; ++c) {            // pub checks, only on change
                if (t == 0) {
                    while (ld_acq(&pub_s[c]) < 1) __builtin_amdgcn_s_sleep(1);
                } else if ((d & ((1 << c) - 1)) == 0) {
                    const int need = (d >> c) + 2;
                    while (ld_acq(&pub_s[c]) < need) __builtin_amdgcn_s_sleep(1);
                }
            }
            const float2 xt = x_s[t + 1];
            float pre0 = xt.x * wihA.x + xt.y * wihA.y + a0s;
            float pre1 = xt.x * wihB.x + xt.y * wihB.y + a1s;
            #pragma unroll
            for (int c = 1; c < 8; ++c) {
                const int slot = (t == 0) ? 1 : ((d >> c) & 1);
                const float2 v = *(const float2*)&Sp[c*(c+1)/2 - 1][slot][R0];
                pre0 += v.x; pre1 += v.y;
            }
            const float hA = fast_tanh(pre0), hB = fast_tanh(pre1);
            if (lane == 0) st_rel(&cons_s[0], t + 1);
            if (t >= 2)                              // protect hbuf slot (wave8)
                while (ld_acq(&outd_s) < t - 1) __builtin_amdgcn_s_sleep(1);
            hbuf[0][t & 1][lane] = packh2(hA, hB);
            if (lane == 0) st_rel(&sd0_s, t + 1);
            mv00(t & 1);                             // S00 for step t+1 (regs)
        }
    } else if (wv == 8) {
        // ================= wave 8: output assembly =========================
        const unsigned f0d = packh2(fc_w[2*lane],       fc_w[2*lane + 1]);
        const unsigned f1d = packh2(fc_w[Hsz + 2*lane], fc_w[Hsz + 2*lane + 1]);
        const float fb0 = fc_b[0], fb1 = fc_b[1];
        float Om0[8], Om1[8];
        #pragma unroll
        for (int m = 0; m < 8; ++m) { Om0[m] = 0.f; Om1[m] = 0.f; }
        float* outb = out + (size_t)b * Tsz * 2;
        for (int t = 0; t < Tsz; ++t) {
            #pragma unroll
            for (int m = 1; m < 8; ++m) {
                if ((t & ((1 << m) - 1)) == 0) {     // module m updated at t
                    const int e = t >> m;
                    while (ld_acq(&pub_s[m]) < e + 2) __builtin_amdgcn_s_sleep(1);
                    Om0[m] = O_s[m][e & 1][0];
                    Om1[m] = O_s[m][e & 1][1];
                }
            }
            while (ld_acq(&sd0_s) < t + 1) __builtin_amdgcn_s_sleep(1);
            const unsigned hd = hbuf[0][t & 1][lane];
            float o0 = fdot2u(hd, f0d, 0.f), o1 = fdot2u(hd, f1d, 0.f);
            #pragma unroll
            for (int o = 1; o < 64; o <<= 1) {
                o0 += __shfl_xor(o0, o, 64);
                o1 += __shfl_xor(o1, o, 64);
            }
            if (lane == 0) {
                float s0 = fb0 + o0, s1 = fb1 + o1;
                #pragma unroll
                for (int m = 1; m < 8; ++m) { s0 += Om0[m]; s1 += Om1[m]; }
                *(float2*)(outb + 2 * t) = make_float2(s0, s1);
            }
            if (lane == 0) st_rel(&outd_s, t + 1);
        }
    } else {
        // ================= waves 1..7: module m + column-m production ======
        const int m  = wv;
        const int R0 = m * MS + 2 * lane, R1 = R0 + 1;
        const float2 wihA = ((const float2*)W_ih)[R0];
        const float2 wihB = ((const float2*)W_ih)[R1];
        const float fA0 = fc_w[R0], fB0 = fc_w[R1];
        const float fA1 = fc_w[Hsz + R0], fB1 = fc_w[Hsz + R1];
        const float2 eA = ((const float2*)enc_w)[R0];
        const float2 eB = ((const float2*)enc_w)[R1];
        const int jh = lane & 1, rql = lane >> 1;

        unsigned hq[32];                             // own h, half jh
        auto load_hq = [&](int slot) {
            const unsigned* hb = &hbuf[m][slot][jh * 32];
            #pragma unroll
            for (int q = 0; q < 8; ++q) {
                const uint4 v = *(const uint4*)(hb + 4 * q);
                hq[4*q]   = v.x; hq[4*q+1] = v.y;
                hq[4*q+2] = v.z; hq[4*q+3] = v.w;
            }
        };
        auto mv = [&](int r, int slot) {             // S[r][m] -> Sp
            const int P = m * (m + 1) / 2 + r;
            const unsigned* wp = WPg + (size_t)P * 8192 + jh * 32;
            float* dst = Sp[P - 1][slot];
            #pragma unroll
            for (int q = 0; q < 4; ++q) {
                const unsigned* wr = wp + (q * 32 + rql) * 64;
                float acc = 0.f;
                #pragma unroll
                for (int s = 0; s < 32; ++s) acc = fdot2u(wr[s], hq[s], acc);
                acc += __shfl_xor(acc, 1, 64);
                if (jh == 0) dst[q * 32 + rql] = acc;
            }
        };
        {   // INIT: h from encoder, publish column-m INIT (slot 1)
            const float2 x0 = x_s[0];
            hbuf[m][1][lane] = packh2(x0.x * eA.x + x0.y * eA.y,
                                      x0.x * eB.x + x0.y * eB.y);
            load_hq(1);
            for (int r = 0; r <= m; ++r) mv(r, 1);
            if (lane == 0) st_rel(&pub_s[m], 1);
        }
        const int KMAX = Tsz >> m;
        for (int k = 0; k < KMAX; ++k) {
            const int t = k << m, d = t - 1;
            for (int c = m + 1; c < 8; ++c) {        // input pubs (slack-rich)
                const int need = (t == 0) ? 1 : ((d >> c) + 2);
                while (ld_acq(&pub_s[c]) < need) __builtin_amdgcn_s_sleep(1);
            }
            const float2 xt = x_s[t + 1];
            float pre0 = xt.x * wihA.x + xt.y * wihA.y;
            float pre1 = xt.x * wihB.x + xt.y * wihB.y;
            for (int c = m; c < 8; ++c) {
                const int slot = (t == 0) ? 1 : ((d >> c) & 1);
                const float2 v = *(const float2*)&Sp[c*(c+1)/2 + m - 1][slot][2*lane];
                pre0 += v.x; pre1 += v.y;
            }
            const float hA = fast_tanh(pre0), hB = fast_tanh(pre1);
            if (lane == 0) st_rel(&cons_s[m], t + 1);
            float p0 = hA * fA0 + hB * fB0, p1 = hA * fA1 + hB * fB1;
            #pragma unroll
            for (int o = 1; o < 64; o <<= 1) {
                p0 += __shfl_xor(p0, o, 64);
                p1 += __shfl_xor(p1, o, 64);
            }
            if (k >= 1) {                            // 2-epoch slot throttle
                const int W = ((k - 1) << m) + 1;
                for (int r = 0; r < m; ++r)
                    while (ld_acq(&cons_s[r]) < W) __builtin_amdgcn_s_sleep(1);
                while (ld_acq(&outd_s) < W) __builtin_amdgcn_s_sleep(1);
            }
            const int slot = k & 1;
            hbuf[m][slot][lane] = packh2(hA, hB);
            if (lane == 0) { O_s[m][slot][0] = p0; O_s[m][slot][1] = p1; }
            load_hq(slot);
            for (int r = 0; r <= m; ++r) mv(r, slot);
            if (lane == 0) st_rel(&pub_s[m], k + 2);
        }
    }
}

// ---------------------------------------------------------------------------
extern "C" void kernel_launch(void* const* d_in, const int* in_sizes, int n_in,
                              void* d_out, int out_size, void* d_ws, size_t ws_size,
                              hipStream_t stream) {
    const float* x     = (const float*)d_in[0];
    const float* W_ih  = (const float*)d_in[1];
    const float* W_hh  = (const float*)d_in[2];
    const float* fc_w  = (const float*)d_in[3];
    const float* fc_b  = (const float*)d_in[4];
    const float* enc_w = (const float*)d_in[5];
    float* outp = (float*)d_out;
    unsigned* WPg = (unsigned*)d_ws;                 // 36*8192*4 = 1.18 MB

    retile<<<36, 256, 0, stream>>>(W_hh, WPg);
    cwrnn_kernel<<<Bsz, NT, 0, stream>>>(x, W_ih, fc_w, fc_b, enc_w, WPg, outp);
}